// Round 2
// 254.874 us; speedup vs baseline: 1.1765x; 1.1765x over previous
//
#include <hip/hip_runtime.h>

typedef unsigned short u16;
typedef __attribute__((ext_vector_type(8))) short bf16x8;   // 8 bf16 in 4 VGPRs (MFMA A/B frag)
typedef __attribute__((ext_vector_type(4))) float f32x4;    // MFMA C/D frag

#define SS 2048
#define EE 1024
#define HH 16
#define DD 64

__device__ __forceinline__ float b2f(u16 u) {
  union { unsigned int i; float f; } v; v.i = ((unsigned int)u) << 16; return v.f;
}
__device__ __forceinline__ u16 f2b(float f) {
  union { float f; unsigned int i; } v; v.f = f;
  unsigned int i = v.i;
  return (u16)((i + 0x7FFFu + ((i >> 16) & 1u)) >> 16);  // RNE
}

// async global->LDS, 16B per lane (m97 pattern; LDS dest = wave-uniform base + lane*16)
#define GLD16(g, l)                                                         \
  __builtin_amdgcn_global_load_lds(                                         \
      (const __attribute__((address_space(1))) unsigned int*)(g),           \
      (__attribute__((address_space(3))) unsigned int*)(l), 16, 0, 0)

// ---------------- fp32 -> bf16 convert (weights) ----------------
__global__ __launch_bounds__(256) void k_cvt(const float* __restrict__ src,
                                             u16* __restrict__ dst) {
  const int i = blockIdx.x * 256 + threadIdx.x;
  float4 v = ((const float4*)src)[i];
  ushort4 o;
  o.x = f2b(v.x); o.y = f2b(v.y); o.z = f2b(v.z); o.w = f2b(v.w);
  ((ushort4*)dst)[i] = o;
}

// ---------------- cos/sin table (1024 entries, computed once) ----------------
__global__ __launch_bounds__(256) void k_trig(const float* __restrict__ inv_freq,
                                              float2* __restrict__ cs) {
  const int i = blockIdx.x * 256 + threadIdx.x;
  float th = 2048.0f * inv_freq[i];
  cs[i] = make_float2(cosf(th), sinf(th));
}

// ---------------- LayerNorm (fp32 in -> bf16 out) ----------------
__global__ __launch_bounds__(256) void k_ln(const float* __restrict__ x,
                                            const float* __restrict__ lw,
                                            const float* __restrict__ lb,
                                            u16* __restrict__ xn) {
  const int row = blockIdx.x, t = threadIdx.x;
  float4 v = ((const float4*)(x + (size_t)row * EE))[t];
  float f0 = v.x, f1 = v.y, f2 = v.z, f3 = v.w;
  float s = f0 + f1 + f2 + f3;
  float ss = f0 * f0 + f1 * f1 + f2 * f2 + f3 * f3;
  for (int o = 1; o < 64; o <<= 1) { s += __shfl_xor(s, o); ss += __shfl_xor(ss, o); }
  __shared__ float red[8];
  int w = t >> 6;
  if ((t & 63) == 0) { red[w] = s; red[4 + w] = ss; }
  __syncthreads();
  s = red[0] + red[1] + red[2] + red[3];
  ss = red[4] + red[5] + red[6] + red[7];
  float mu = s * (1.0f / 1024.0f);
  float var = ss * (1.0f / 1024.0f) - mu * mu;
  float rstd = rsqrtf(var + 1e-5f);
  float4 wv = ((const float4*)lw)[t];
  float4 bv = ((const float4*)lb)[t];
  ushort4 o;
  o.x = f2b((f0 - mu) * rstd * wv.x + bv.x);
  o.y = f2b((f1 - mu) * rstd * wv.y + bv.y);
  o.z = f2b((f2 - mu) * rstd * wv.z + bv.z);
  o.w = f2b((f3 - mu) * rstd * wv.w + bv.w);
  ((ushort4*)(xn + (size_t)row * EE))[t] = o;
}

// ---- MFMA GEMM  C[M,N] = A[M,K] * W[N,K]^T + bias; bf16 or fp32 output ----
// m97 structure: 128x128 tile, BK=32, linear LDS (stride 32), global_load_lds x16
template <typename OutT>
__device__ __forceinline__ void gemm_body(const u16* __restrict__ A,
                                          const u16* __restrict__ W,
                                          const float* __restrict__ bias,
                                          OutT* __restrict__ C,
                                          int M, int N, int K) {
  __shared__ __align__(16) u16 As[128 * 32];
  __shared__ __align__(16) u16 Ws[128 * 32];
  const int t = threadIdx.x;
  const int m0 = blockIdx.y * 128, n0 = blockIdx.x * 128;
  const int lane = t & 63, w = t >> 6, quad = lane >> 4, l15 = lane & 15;
  const int wm = (w & 1) * 64, wn = (w >> 1) * 64;

  f32x4 zero4 = {0.f, 0.f, 0.f, 0.f};
  f32x4 acc[4][4];
  for (int mi = 0; mi < 4; mi++)
    for (int ni = 0; ni < 4; ni++) acc[mi][ni] = zero4;

  // staging: thread t owns row t>>2, 8 cols at (t&3)*8 -> LDS linear at t*8 (u16)
  const u16* Ag = A + (size_t)(m0 + (t >> 2)) * K + (t & 3) * 8;
  const u16* Wg = W + (size_t)(n0 + (t >> 2)) * K + (t & 3) * 8;
  const size_t rowskip = (size_t)64 * K;

  for (int k0 = 0; k0 < K; k0 += 32) {
    GLD16(Ag + k0, As + t * 8);
    GLD16(Ag + rowskip + k0, As + 2048 + t * 8);
    GLD16(Wg + k0, Ws + t * 8);
    GLD16(Wg + rowskip + k0, Ws + 2048 + t * 8);
    __syncthreads();
    bf16x8 af[4], wf[4];
#pragma unroll
    for (int i = 0; i < 4; i++) {
      af[i] = *(const bf16x8*)(As + (wm + i * 16 + l15) * 32 + quad * 8);
      wf[i] = *(const bf16x8*)(Ws + (wn + i * 16 + l15) * 32 + quad * 8);
    }
#pragma unroll
    for (int mi = 0; mi < 4; mi++)
#pragma unroll
      for (int ni = 0; ni < 4; ni++)
        acc[mi][ni] = __builtin_amdgcn_mfma_f32_16x16x32_bf16(af[mi], wf[ni], acc[mi][ni], 0, 0, 0);
    __syncthreads();
  }
  // epilogue: D row = quad*4+reg, col = l15 (verified m89 layout)
  for (int mi = 0; mi < 4; mi++)
    for (int ni = 0; ni < 4; ni++) {
      int col = n0 + wn + ni * 16 + l15;
      float bb = bias[col];
      for (int r = 0; r < 4; r++) {
        int grow = m0 + wm + mi * 16 + quad * 4 + r;
        float val = acc[mi][ni][r] + bb;
        if constexpr (sizeof(OutT) == 2) C[(size_t)grow * N + col] = f2b(val);
        else                             C[(size_t)grow * N + col] = val;
      }
    }
}

__global__ __launch_bounds__(256) void k_gemm_b(const u16* A, const u16* W,
                                                const float* bias, u16* C,
                                                int M, int N, int K) {
  gemm_body<u16>(A, W, bias, C, M, N, K);
}
__global__ __launch_bounds__(256) void k_gemm_f(const u16* A, const u16* W,
                                                const float* bias, float* C,
                                                int M, int N, int K) {
  gemm_body<float>(A, W, bias, C, M, N, K);
}

// ------ rotate (fixed angle, table) + per-head l2norm + qknorm scale ------
__global__ __launch_bounds__(256) void k_rotnorm(u16* __restrict__ qkv,
                                                 const float2* __restrict__ cs_tab,
                                                 const float* __restrict__ scale_p) {
  __shared__ float qf[1024];
  __shared__ float kf[1024];
  const int row = blockIdx.x, t = threadIdx.x;
  u16* qr = qkv + (size_t)row * 3072;
  u16* kr = qr + 1024;
  ushort4 qv = ((const ushort4*)qr)[t];
  ushort4 kv = ((const ushort4*)kr)[t];
  *(float4*)(qf + 4 * t) = make_float4(b2f(qv.x), b2f(qv.y), b2f(qv.z), b2f(qv.w));
  *(float4*)(kf + 4 * t) = make_float4(b2f(kv.x), b2f(kv.y), b2f(kv.z), b2f(kv.w));
  __syncthreads();
  const float scale = scale_p[0];
  float rq[4], rk[4];
#pragma unroll
  for (int u = 0; u < 4; u++) {
    int j = 4 * t + u;
    float2 cs = cs_tab[j];
    float qrot = (j < 512) ? -qf[2 * j + 1] : qf[2 * (j - 512)];
    float krot = (j < 512) ? -kf[2 * j + 1] : kf[2 * (j - 512)];
    rq[u] = qf[j] * cs.x + qrot * cs.y;
    rk[u] = kf[j] * cs.x + krot * cs.y;
  }
  float ssq = rq[0] * rq[0] + rq[1] * rq[1] + rq[2] * rq[2] + rq[3] * rq[3];
  float ssk = rk[0] * rk[0] + rk[1] * rk[1] + rk[2] * rk[2] + rk[3] * rk[3];
  for (int o = 1; o < 16; o <<= 1) { ssq += __shfl_xor(ssq, o); ssk += __shfl_xor(ssk, o); }
  float qs = scale / fmaxf(sqrtf(ssq), 1e-12f);
  float ks = scale / fmaxf(sqrtf(ssk), 1e-12f);
  ushort4 qo, ko;
  qo.x = f2b(rq[0] * qs); qo.y = f2b(rq[1] * qs); qo.z = f2b(rq[2] * qs); qo.w = f2b(rq[3] * qs);
  ko.x = f2b(rk[0] * ks); ko.y = f2b(rk[1] * ks); ko.z = f2b(rk[2] * ks); ko.w = f2b(rk[3] * ks);
  ((ushort4*)qr)[t] = qo;
  ((ushort4*)kr)[t] = ko;
}

// ---------------- V transpose -> vt[(b,h), d, s] ----------------
// tile stride 72 u16 (144 B = 9x16B): b128 reads stay 16B-aligned for every row
__global__ __launch_bounds__(256) void k_vtrans(const u16* __restrict__ qkv,
                                                u16* __restrict__ vt) {
  __shared__ __align__(16) u16 tile[64 * 72];
  const int st = blockIdx.x, bh = blockIdx.y;
  const int b = bh >> 4, h = bh & 15;
  const int s0 = st * 64, t = threadIdx.x;
  const int si = t >> 2, dc = t & 3;
  const u16* src = qkv + (size_t)(b * SS + s0 + si) * 3072 + 2048 + h * DD;
  bf16x8 v0 = *(const bf16x8*)(src + dc * 8);
  bf16x8 v1 = *(const bf16x8*)(src + (dc + 4) * 8);
#pragma unroll
  for (int u = 0; u < 8; u++) tile[(dc * 8 + u) * 72 + si] = (u16)v0[u];
#pragma unroll
  for (int u = 0; u < 8; u++) tile[((dc + 4) * 8 + u) * 72 + si] = (u16)v1[u];
  __syncthreads();
#pragma unroll
  for (int it = 0; it < 2; it++) {
    int idx = t + it * 256;
    int d = idx >> 3, ch = idx & 7;
    bf16x8 o = *(const bf16x8*)(tile + d * 72 + ch * 8);
    *(bf16x8*)(vt + (size_t)(bh * DD + d) * SS + s0 + ch * 8) = o;
  }
}

// ---------------- causal flash attention (MFMA) ----------------
// paired q-tiles (qt, 31-qt): every block does exactly 33 kt-iterations
// all LDS tiles stride 72 u16 (144 B): 16B-aligned b128 rows, read-side conflict-optimal
__global__ __launch_bounds__(256) void k_attn(const u16* __restrict__ qkv,
                                              const u16* __restrict__ vt,
                                              u16* __restrict__ out) {
  __shared__ __align__(16) u16 Kt[64 * 72];
  __shared__ __align__(16) u16 Vt[64 * 72];
  __shared__ __align__(16) u16 Pt[64 * 72];
  const int bh = blockIdx.y;
  const int b = bh >> 4, h = bh & 15;
  const int t = threadIdx.x, w = t >> 6, lane = t & 63, quad = lane >> 4, l15 = lane & 15;
  const int sr = t >> 2, sc = t & 3;
  const u16* qn = qkv;
  const u16* kn = qkv + 1024;
  f32x4 zero4 = {0.f, 0.f, 0.f, 0.f};

  for (int rep = 0; rep < 2; rep++) {
    const int qt = rep ? 31 - (int)blockIdx.x : (int)blockIdx.x;
    const int q0 = qt * 64;

    bf16x8 qf[2];
    {
      const u16* qrow = qn + (size_t)(b * SS + q0 + 16 * w + l15) * 3072 + h * DD;
      qf[0] = *(const bf16x8*)(qrow + quad * 8);
      qf[1] = *(const bf16x8*)(qrow + 32 + quad * 8);
    }
    f32x4 oacc[4];
    for (int n = 0; n < 4; n++) oacc[n] = zero4;
    float m_i[4] = {-1e30f, -1e30f, -1e30f, -1e30f};
    float l_i[4] = {0.f, 0.f, 0.f, 0.f};

    for (int kt = 0; kt <= qt; kt++) {
      const int k0 = kt * 64;
      const u16* krow = kn + (size_t)(b * SS + k0 + sr) * 3072 + h * DD;
      bf16x8 kv0 = *(const bf16x8*)(krow + sc * 8);
      bf16x8 kv1 = *(const bf16x8*)(krow + (sc + 4) * 8);
      const u16* vrow = vt + (size_t)(bh * DD + sr) * SS + k0;
      bf16x8 vv0 = *(const bf16x8*)(vrow + sc * 8);
      bf16x8 vv1 = *(const bf16x8*)(vrow + (sc + 4) * 8);
      *(bf16x8*)(Kt + sr * 72 + sc * 8) = kv0;
      *(bf16x8*)(Kt + sr * 72 + (sc + 4) * 8) = kv1;
      *(bf16x8*)(Vt + sr * 72 + sc * 8) = vv0;
      *(bf16x8*)(Vt + sr * 72 + (sc + 4) * 8) = vv1;
      __syncthreads();
      f32x4 sacc[4];
#pragma unroll
      for (int n = 0; n < 4; n++) {
        sacc[n] = zero4;
#pragma unroll
        for (int c = 0; c < 2; c++) {
          bf16x8 kfrag = *(const bf16x8*)(Kt + (n * 16 + l15) * 72 + c * 32 + quad * 8);
          sacc[n] = __builtin_amdgcn_mfma_f32_16x16x32_bf16(qf[c], kfrag, sacc[n], 0, 0, 0);
        }
      }
      if (kt == qt) {
#pragma unroll
        for (int n = 0; n < 4; n++)
#pragma unroll
          for (int r = 0; r < 4; r++)
            if (n * 16 + l15 > 16 * w + quad * 4 + r) sacc[n][r] = -1e30f;
      }
#pragma unroll
      for (int r = 0; r < 4; r++) {
        float mx = fmaxf(fmaxf(sacc[0][r], sacc[1][r]), fmaxf(sacc[2][r], sacc[3][r]));
        for (int o = 1; o < 16; o <<= 1) mx = fmaxf(mx, __shfl_xor(mx, o));
        float mn = fmaxf(m_i[r], mx);
        float al = __expf(m_i[r] - mn);
        m_i[r] = mn;
        float rs = 0.f;
#pragma unroll
        for (int n = 0; n < 4; n++) {
          float p = __expf(sacc[n][r] - mn);
          sacc[n][r] = p;
          rs += p;
        }
        for (int o = 1; o < 16; o <<= 1) rs += __shfl_xor(rs, o);
        l_i[r] = al * l_i[r] + rs;
#pragma unroll
        for (int n = 0; n < 4; n++) oacc[n][r] *= al;
      }
#pragma unroll
      for (int n = 0; n < 4; n++)
#pragma unroll
        for (int r = 0; r < 4; r++)
          Pt[(16 * w + quad * 4 + r) * 72 + n * 16 + l15] = f2b(sacc[n][r]);
      __syncthreads();
#pragma unroll
      for (int c = 0; c < 2; c++) {
        bf16x8 pf = *(const bf16x8*)(Pt + (16 * w + l15) * 72 + c * 32 + quad * 8);
#pragma unroll
        for (int n = 0; n < 4; n++) {
          bf16x8 vf = *(const bf16x8*)(Vt + (n * 16 + l15) * 72 + c * 32 + quad * 8);
          oacc[n] = __builtin_amdgcn_mfma_f32_16x16x32_bf16(pf, vf, oacc[n], 0, 0, 0);
        }
      }
      __syncthreads();
    }
    for (int n = 0; n < 4; n++)
      for (int r = 0; r < 4; r++) {
        int row = q0 + 16 * w + quad * 4 + r;
        out[(size_t)(b * SS + row) * EE + h * DD + n * 16 + l15] = f2b(oacc[n][r] / l_i[r]);
      }
  }
}

extern "C" void kernel_launch(void* const* d_in, const int* in_sizes, int n_in,
                              void* d_out, int out_size, void* d_ws, size_t ws_size,
                              hipStream_t stream) {
  const float* x       = (const float*)d_in[0];
  const float* ln_w    = (const float*)d_in[1];
  const float* ln_b    = (const float*)d_in[2];
  const float* qkv_w   = (const float*)d_in[3];
  const float* qkv_b   = (const float*)d_in[4];
  const float* qk_s    = (const float*)d_in[5];
  const float* out_w   = (const float*)d_in[6];
  const float* out_b   = (const float*)d_in[7];
  const float* inv_frq = (const float*)d_in[8];

  // ws (33.55 MB): xn bf16 [8.39 MB] | qkv bf16 [25.17 MB]
  u16* ws   = (u16*)d_ws;
  u16* xn   = ws;                               // 4096*1024 (LN out, later attn out)
  u16* qkv  = ws + (size_t)4096 * 1024;         // 4096*3072 (q,k normalized in place)
  // d_out is fp32 [16.78 MB]; stage bf16 scratch inside it while it's dead:
  u16* wq_b = (u16*)d_out;                      // [0, 6.29 MB): bf16 qkv_w
  float2* cs_tab = (float2*)((char*)d_out + 6291456);  // [6.29, 6.30 MB): cos/sin table
  u16* vt   = (u16*)d_out + (size_t)4194304;    // [8.39, 16.78 MB): bf16 V^T
  u16* wo_b = qkv;                              // bf16 out_w (qkv dead after attention)

  k_cvt<<<3072, 256, 0, stream>>>(qkv_w, wq_b);
  k_trig<<<4, 256, 0, stream>>>(inv_frq, cs_tab);
  k_ln<<<4096, 256, 0, stream>>>(x, ln_w, ln_b, xn);
  k_gemm_b<<<dim3(24, 32), 256, 0, stream>>>(xn, wq_b, qkv_b, qkv, 4096, 3072, 1024);
  k_rotnorm<<<4096, 256, 0, stream>>>(qkv, cs_tab, qk_s);
  k_vtrans<<<dim3(32, 32), 256, 0, stream>>>(qkv, vt);
  k_attn<<<dim3(16, 32), 256, 0, stream>>>(qkv, vt, xn);
  k_cvt<<<1024, 256, 0, stream>>>(out_w, wo_b);
  k_gemm_f<<<dim3(8, 32), 256, 0, stream>>>(xn, wo_b, out_b, (float*)d_out, 4096, 1024, 1024);
}

// Round 3
// 239.519 us; speedup vs baseline: 1.2519x; 1.0641x over previous
//
#include <hip/hip_runtime.h>

typedef unsigned short u16;
typedef __attribute__((ext_vector_type(8))) short bf16x8;   // 8 bf16 in 4 VGPRs (MFMA A/B frag)
typedef __attribute__((ext_vector_type(4))) float f32x4;    // MFMA C/D frag

#define SS 2048
#define EE 1024
#define HH 16
#define DD 64

__device__ __forceinline__ float b2f(u16 u) {
  union { unsigned int i; float f; } v; v.i = ((unsigned int)u) << 16; return v.f;
}
__device__ __forceinline__ u16 f2b(float f) {
  union { float f; unsigned int i; } v; v.f = f;
  unsigned int i = v.i;
  return (u16)((i + 0x7FFFu + ((i >> 16) & 1u)) >> 16);  // RNE
}

// async global->LDS, 16B per lane (m97 pattern; LDS dest = wave-uniform base + lane*16)
#define GLD16(g, l)                                                         \
  __builtin_amdgcn_global_load_lds(                                         \
      (const __attribute__((address_space(1))) unsigned int*)(g),           \
      (__attribute__((address_space(3))) unsigned int*)(l), 16, 0, 0)

// ---------------- fused prep: qkv_w cvt | trig table | LayerNorm ----------------
// blocks [0,3072): cvt qkv_w -> bf16; [3072,3076): cos/sin table; [3076,7172): LN rows
__global__ __launch_bounds__(256) void k_prep(const float* __restrict__ qkv_w,
                                              u16* __restrict__ wq_b,
                                              const float* __restrict__ inv_freq,
                                              float2* __restrict__ cs,
                                              const float* __restrict__ x,
                                              const float* __restrict__ lw,
                                              const float* __restrict__ lb,
                                              u16* __restrict__ xn) {
  const int bx = blockIdx.x, t = threadIdx.x;
  if (bx < 3072) {
    const int i = bx * 256 + t;
    float4 v = ((const float4*)qkv_w)[i];
    ushort4 o;
    o.x = f2b(v.x); o.y = f2b(v.y); o.z = f2b(v.z); o.w = f2b(v.w);
    ((ushort4*)wq_b)[i] = o;
    return;
  }
  if (bx < 3076) {
    const int i = (bx - 3072) * 256 + t;
    float th = 2048.0f * inv_freq[i];
    cs[i] = make_float2(cosf(th), sinf(th));
    return;
  }
  const int row = bx - 3076;
  float4 v = ((const float4*)(x + (size_t)row * EE))[t];
  float f0 = v.x, f1 = v.y, f2 = v.z, f3 = v.w;
  float s = f0 + f1 + f2 + f3;
  float ss = f0 * f0 + f1 * f1 + f2 * f2 + f3 * f3;
  for (int o = 1; o < 64; o <<= 1) { s += __shfl_xor(s, o); ss += __shfl_xor(ss, o); }
  __shared__ float red[8];
  int w = t >> 6;
  if ((t & 63) == 0) { red[w] = s; red[4 + w] = ss; }
  __syncthreads();
  s = red[0] + red[1] + red[2] + red[3];
  ss = red[4] + red[5] + red[6] + red[7];
  float mu = s * (1.0f / 1024.0f);
  float var = ss * (1.0f / 1024.0f) - mu * mu;
  float rstd = rsqrtf(var + 1e-5f);
  float4 wv = ((const float4*)lw)[t];
  float4 bv = ((const float4*)lb)[t];
  ushort4 o;
  o.x = f2b((f0 - mu) * rstd * wv.x + bv.x);
  o.y = f2b((f1 - mu) * rstd * wv.y + bv.y);
  o.z = f2b((f2 - mu) * rstd * wv.z + bv.z);
  o.w = f2b((f3 - mu) * rstd * wv.w + bv.w);
  ((ushort4*)(xn + (size_t)row * EE))[t] = o;
}

// ---------------- fp32 -> bf16 convert (out_w, after attn frees qkv) ----------------
__global__ __launch_bounds__(256) void k_cvt(const float* __restrict__ src,
                                             u16* __restrict__ dst) {
  const int i = blockIdx.x * 256 + threadIdx.x;
  float4 v = ((const float4*)src)[i];
  ushort4 o;
  o.x = f2b(v.x); o.y = f2b(v.y); o.z = f2b(v.z); o.w = f2b(v.w);
  ((ushort4*)dst)[i] = o;
}

// ---- MFMA GEMM  C[M,N] = A[M,K] * W[N,K]^T + bias ----
// m97 structure: BMx128 tile (BM=64 or 128), BK=32, linear LDS, global_load_lds x16
template <typename OutT, int BM64>
__device__ __forceinline__ void gemm_body(const u16* __restrict__ A,
                                          const u16* __restrict__ W,
                                          const float* __restrict__ bias,
                                          OutT* __restrict__ C,
                                          int M, int N, int K) {
  constexpr int BM = 64 * BM64;
  constexpr int MI = 2 * BM64;
  __shared__ __align__(16) u16 As[BM * 32];
  __shared__ __align__(16) u16 Ws[128 * 32];
  const int t = threadIdx.x;
  const int m0 = blockIdx.y * BM, n0 = blockIdx.x * 128;
  const int lane = t & 63, w = t >> 6, quad = lane >> 4, l15 = lane & 15;
  const int wm = (w & 1) * (BM / 2), wn = (w >> 1) * 64;

  f32x4 zero4 = {0.f, 0.f, 0.f, 0.f};
  f32x4 acc[MI][4];
  for (int mi = 0; mi < MI; mi++)
    for (int ni = 0; ni < 4; ni++) acc[mi][ni] = zero4;

  const u16* Ag = A + (size_t)(m0 + (t >> 2)) * K + (t & 3) * 8;
  const u16* Wg = W + (size_t)(n0 + (t >> 2)) * K + (t & 3) * 8;
  const size_t rowskip = (size_t)64 * K;

  for (int k0 = 0; k0 < K; k0 += 32) {
    GLD16(Ag + k0, As + t * 8);
    if constexpr (BM64 == 2) GLD16(Ag + rowskip + k0, As + 2048 + t * 8);
    GLD16(Wg + k0, Ws + t * 8);
    GLD16(Wg + rowskip + k0, Ws + 2048 + t * 8);
    __syncthreads();
    bf16x8 af[MI], wf[4];
#pragma unroll
    for (int i = 0; i < MI; i++)
      af[i] = *(const bf16x8*)(As + (wm + i * 16 + l15) * 32 + quad * 8);
#pragma unroll
    for (int i = 0; i < 4; i++)
      wf[i] = *(const bf16x8*)(Ws + (wn + i * 16 + l15) * 32 + quad * 8);
#pragma unroll
    for (int mi = 0; mi < MI; mi++)
#pragma unroll
      for (int ni = 0; ni < 4; ni++)
        acc[mi][ni] = __builtin_amdgcn_mfma_f32_16x16x32_bf16(af[mi], wf[ni], acc[mi][ni], 0, 0, 0);
    __syncthreads();
  }
  // epilogue: D row = quad*4+reg, col = l15 (verified m89 layout)
  for (int mi = 0; mi < MI; mi++)
    for (int ni = 0; ni < 4; ni++) {
      int col = n0 + wn + ni * 16 + l15;
      float bb = bias[col];
      for (int r = 0; r < 4; r++) {
        int grow = m0 + wm + mi * 16 + quad * 4 + r;
        float val = acc[mi][ni][r] + bb;
        if constexpr (sizeof(OutT) == 2) C[(size_t)grow * N + col] = f2b(val);
        else                             C[(size_t)grow * N + col] = val;
      }
    }
}

__global__ __launch_bounds__(256) void k_gemm_b(const u16* A, const u16* W,
                                                const float* bias, u16* C,
                                                int M, int N, int K) {
  gemm_body<u16, 2>(A, W, bias, C, M, N, K);
}
__global__ __launch_bounds__(256) void k_gemm_f(const u16* A, const u16* W,
                                                const float* bias, float* C,
                                                int M, int N, int K) {
  gemm_body<float, 1>(A, W, bias, C, M, N, K);
}

// ------ fused: rotate+l2norm+scale (all 4096 rows) | V transpose (blocks < 1024) ------
__global__ __launch_bounds__(256) void k_rotv(u16* __restrict__ qkv,
                                              const float2* __restrict__ cs_tab,
                                              const float* __restrict__ scale_p,
                                              u16* __restrict__ vt) {
  __shared__ float qf[1024];
  __shared__ float kf[1024];
  __shared__ __align__(16) u16 tile[64 * 72];
  const int row = blockIdx.x, t = threadIdx.x;
  {
    u16* qr = qkv + (size_t)row * 3072;
    u16* kr = qr + 1024;
    ushort4 qv = ((const ushort4*)qr)[t];
    ushort4 kv = ((const ushort4*)kr)[t];
    *(float4*)(qf + 4 * t) = make_float4(b2f(qv.x), b2f(qv.y), b2f(qv.z), b2f(qv.w));
    *(float4*)(kf + 4 * t) = make_float4(b2f(kv.x), b2f(kv.y), b2f(kv.z), b2f(kv.w));
    __syncthreads();
    const float scale = scale_p[0];
    float rq[4], rk[4];
#pragma unroll
    for (int u = 0; u < 4; u++) {
      int j = 4 * t + u;
      float2 cs = cs_tab[j];
      float qrot = (j < 512) ? -qf[2 * j + 1] : qf[2 * (j - 512)];
      float krot = (j < 512) ? -kf[2 * j + 1] : kf[2 * (j - 512)];
      rq[u] = qf[j] * cs.x + qrot * cs.y;
      rk[u] = kf[j] * cs.x + krot * cs.y;
    }
    float ssq = rq[0] * rq[0] + rq[1] * rq[1] + rq[2] * rq[2] + rq[3] * rq[3];
    float ssk = rk[0] * rk[0] + rk[1] * rk[1] + rk[2] * rk[2] + rk[3] * rk[3];
    for (int o = 1; o < 16; o <<= 1) { ssq += __shfl_xor(ssq, o); ssk += __shfl_xor(ssk, o); }
    float qs = scale / fmaxf(sqrtf(ssq), 1e-12f);
    float ks = scale / fmaxf(sqrtf(ssk), 1e-12f);
    ushort4 qo, ko;
    qo.x = f2b(rq[0] * qs); qo.y = f2b(rq[1] * qs); qo.z = f2b(rq[2] * qs); qo.w = f2b(rq[3] * qs);
    ko.x = f2b(rk[0] * ks); ko.y = f2b(rk[1] * ks); ko.z = f2b(rk[2] * ks); ko.w = f2b(rk[3] * ks);
    ((ushort4*)qr)[t] = qo;
    ((ushort4*)kr)[t] = ko;
  }
  if (row >= 1024) return;
  // ---- V transpose job (reads V section: untouched by the rotnorm phase) ----
  const int st = row & 31, bh = row >> 5;
  const int b = bh >> 4, h = bh & 15;
  const int s0 = st * 64;
  const int si = t >> 2, dc = t & 3;
  __syncthreads();  // LDS reuse safety (qf/kf reads done before tile writes)
  const u16* src = qkv + (size_t)(b * SS + s0 + si) * 3072 + 2048 + h * DD;
  bf16x8 v0 = *(const bf16x8*)(src + dc * 8);
  bf16x8 v1 = *(const bf16x8*)(src + (dc + 4) * 8);
#pragma unroll
  for (int u = 0; u < 8; u++) tile[(dc * 8 + u) * 72 + si] = (u16)v0[u];
#pragma unroll
  for (int u = 0; u < 8; u++) tile[((dc + 4) * 8 + u) * 72 + si] = (u16)v1[u];
  __syncthreads();
#pragma unroll
  for (int it = 0; it < 2; it++) {
    int idx = t + it * 256;
    int d = idx >> 3, ch = idx & 7;
    bf16x8 o = *(const bf16x8*)(tile + d * 72 + ch * 8);
    *(bf16x8*)(vt + (size_t)(bh * DD + d) * SS + s0 + ch * 8) = o;
  }
}

// ---------------- causal flash attention (MFMA) ----------------
// paired q-tiles (qt, 31-qt): every block does exactly 33 kt-iterations.
// double-buffered K/V with async prefetch (T14); ONE barrier per iteration
// (Pt is warp-private: warp w writes and reads only rows [16w,16w+16)).
__global__ __launch_bounds__(256) void k_attn(const u16* __restrict__ qkv,
                                              const u16* __restrict__ vt,
                                              u16* __restrict__ out) {
  __shared__ __align__(16) u16 Kt[2][64 * 72];
  __shared__ __align__(16) u16 Vt[2][64 * 72];
  __shared__ __align__(16) u16 Pt[64 * 72];
  const int bh = blockIdx.y;
  const int b = bh >> 4, h = bh & 15;
  const int t = threadIdx.x, w = t >> 6, lane = t & 63, quad = lane >> 4, l15 = lane & 15;
  const int sr = t >> 2, sc = t & 3;
  const u16* kn = qkv + 1024;
  f32x4 zero4 = {0.f, 0.f, 0.f, 0.f};

  for (int rep = 0; rep < 2; rep++) {
    const int qt = rep ? 31 - (int)blockIdx.x : (int)blockIdx.x;
    const int q0 = qt * 64;

    bf16x8 qf[2];
    {
      const u16* qrow = qkv + (size_t)(b * SS + q0 + 16 * w + l15) * 3072 + h * DD;
      qf[0] = *(const bf16x8*)(qrow + quad * 8);
      qf[1] = *(const bf16x8*)(qrow + 32 + quad * 8);
    }
    f32x4 oacc[4];
    for (int n = 0; n < 4; n++) oacc[n] = zero4;
    float m_i[4] = {-1e30f, -1e30f, -1e30f, -1e30f};
    float l_i[4] = {0.f, 0.f, 0.f, 0.f};

    // prologue: stage tile kt=0 into buf 0
    bf16x8 kv0, kv1, vv0, vv1;
    {
      const u16* krow = kn + (size_t)(b * SS + sr) * 3072 + h * DD;
      kv0 = *(const bf16x8*)(krow + sc * 8);
      kv1 = *(const bf16x8*)(krow + (sc + 4) * 8);
      const u16* vrow = vt + (size_t)(bh * DD + sr) * SS;
      vv0 = *(const bf16x8*)(vrow + sc * 8);
      vv1 = *(const bf16x8*)(vrow + (sc + 4) * 8);
    }
    __syncthreads();  // previous rep's readers done before overwriting buffers
    *(bf16x8*)(Kt[0] + sr * 72 + sc * 8) = kv0;
    *(bf16x8*)(Kt[0] + sr * 72 + (sc + 4) * 8) = kv1;
    *(bf16x8*)(Vt[0] + sr * 72 + sc * 8) = vv0;
    *(bf16x8*)(Vt[0] + sr * 72 + (sc + 4) * 8) = vv1;
    int cur = 0;

    for (int kt = 0; kt <= qt; kt++) {
      __syncthreads();  // buf[cur] staged; all reads of buf[cur^1] finished
      if (kt < qt) {    // prefetch next tile into regs (consumed at loop bottom)
        const int k0n = (kt + 1) * 64;
        const u16* krow = kn + (size_t)(b * SS + k0n + sr) * 3072 + h * DD;
        kv0 = *(const bf16x8*)(krow + sc * 8);
        kv1 = *(const bf16x8*)(krow + (sc + 4) * 8);
        const u16* vrow = vt + (size_t)(bh * DD + sr) * SS + k0n;
        vv0 = *(const bf16x8*)(vrow + sc * 8);
        vv1 = *(const bf16x8*)(vrow + (sc + 4) * 8);
      }
      const u16* Kc = Kt[cur];
      const u16* Vc = Vt[cur];
      f32x4 sacc[4];
#pragma unroll
      for (int n = 0; n < 4; n++) {
        sacc[n] = zero4;
#pragma unroll
        for (int c = 0; c < 2; c++) {
          bf16x8 kfrag = *(const bf16x8*)(Kc + (n * 16 + l15) * 72 + c * 32 + quad * 8);
          sacc[n] = __builtin_amdgcn_mfma_f32_16x16x32_bf16(qf[c], kfrag, sacc[n], 0, 0, 0);
        }
      }
      if (kt == qt) {
#pragma unroll
        for (int n = 0; n < 4; n++)
#pragma unroll
          for (int r = 0; r < 4; r++)
            if (n * 16 + l15 > 16 * w + quad * 4 + r) sacc[n][r] = -1e30f;
      }
#pragma unroll
      for (int r = 0; r < 4; r++) {
        float mx = fmaxf(fmaxf(sacc[0][r], sacc[1][r]), fmaxf(sacc[2][r], sacc[3][r]));
        for (int o = 1; o < 16; o <<= 1) mx = fmaxf(mx, __shfl_xor(mx, o));
        float mn = fmaxf(m_i[r], mx);
        float al = __expf(m_i[r] - mn);
        m_i[r] = mn;
        float rs = 0.f;
#pragma unroll
        for (int n = 0; n < 4; n++) {
          float p = __expf(sacc[n][r] - mn);
          sacc[n][r] = p;
          rs += p;
        }
        for (int o = 1; o < 16; o <<= 1) rs += __shfl_xor(rs, o);
        l_i[r] = al * l_i[r] + rs;
#pragma unroll
        for (int n = 0; n < 4; n++) oacc[n][r] *= al;
      }
#pragma unroll
      for (int n = 0; n < 4; n++)
#pragma unroll
        for (int r = 0; r < 4; r++)
          Pt[(16 * w + quad * 4 + r) * 72 + n * 16 + l15] = f2b(sacc[n][r]);
      // Pt rows are warp-private; no cross-warp barrier needed, only LDS completion
      asm volatile("s_waitcnt lgkmcnt(0)" ::: "memory");
#pragma unroll
      for (int c = 0; c < 2; c++) {
        bf16x8 pf = *(const bf16x8*)(Pt + (16 * w + l15) * 72 + c * 32 + quad * 8);
#pragma unroll
        for (int n = 0; n < 4; n++) {
          bf16x8 vf = *(const bf16x8*)(Vc + (n * 16 + l15) * 72 + c * 32 + quad * 8);
          oacc[n] = __builtin_amdgcn_mfma_f32_16x16x32_bf16(pf, vf, oacc[n], 0, 0, 0);
        }
      }
      if (kt < qt) {  // stage prefetched tile into the other buffer
        u16* Kn2 = Kt[cur ^ 1];
        u16* Vn2 = Vt[cur ^ 1];
        *(bf16x8*)(Kn2 + sr * 72 + sc * 8) = kv0;
        *(bf16x8*)(Kn2 + sr * 72 + (sc + 4) * 8) = kv1;
        *(bf16x8*)(Vn2 + sr * 72 + sc * 8) = vv0;
        *(bf16x8*)(Vn2 + sr * 72 + (sc + 4) * 8) = vv1;
      }
      cur ^= 1;
    }
    for (int n = 0; n < 4; n++)
      for (int r = 0; r < 4; r++) {
        int row = q0 + 16 * w + quad * 4 + r;
        out[(size_t)(b * SS + row) * EE + h * DD + n * 16 + l15] = f2b(oacc[n][r] / l_i[r]);
      }
  }
}

extern "C" void kernel_launch(void* const* d_in, const int* in_sizes, int n_in,
                              void* d_out, int out_size, void* d_ws, size_t ws_size,
                              hipStream_t stream) {
  const float* x       = (const float*)d_in[0];
  const float* ln_w    = (const float*)d_in[1];
  const float* ln_b    = (const float*)d_in[2];
  const float* qkv_w   = (const float*)d_in[3];
  const float* qkv_b   = (const float*)d_in[4];
  const float* qk_s    = (const float*)d_in[5];
  const float* out_w   = (const float*)d_in[6];
  const float* out_b   = (const float*)d_in[7];
  const float* inv_frq = (const float*)d_in[8];

  // ws (33.55 MB): xn bf16 [8.39 MB] | qkv bf16 [25.17 MB]
  u16* ws   = (u16*)d_ws;
  u16* xn   = ws;                               // 4096*1024 (LN out, later attn out)
  u16* qkv  = ws + (size_t)4096 * 1024;         // 4096*3072 (q,k normalized in place)
  // d_out is fp32 [16.78 MB]; stage bf16 scratch inside it while it's dead:
  u16* wq_b = (u16*)d_out;                      // [0, 6.29 MB): bf16 qkv_w
  float2* cs_tab = (float2*)((char*)d_out + 6291456);  // [6.29, 6.30 MB): cos/sin table
  u16* vt   = (u16*)d_out + (size_t)4194304;    // [8.39, 16.78 MB): bf16 V^T
  u16* wo_b = qkv;                              // bf16 out_w (qkv dead after attention)

  k_prep<<<7172, 256, 0, stream>>>(qkv_w, wq_b, inv_frq, cs_tab, x, ln_w, ln_b, xn);
  k_gemm_b<<<dim3(24, 32), 256, 0, stream>>>(xn, wq_b, qkv_b, qkv, 4096, 3072, 1024);
  k_rotv<<<4096, 256, 0, stream>>>(qkv, cs_tab, qk_s, vt);
  k_attn<<<dim3(16, 32), 256, 0, stream>>>(qkv, vt, xn);
  k_cvt<<<1024, 256, 0, stream>>>(out_w, wo_b);
  k_gemm_f<<<dim3(8, 64), 256, 0, stream>>>(xn, wo_b, out_b, (float*)d_out, 4096, 1024, 1024);
}

// Round 4
// 228.106 us; speedup vs baseline: 1.3146x; 1.0500x over previous
//
#include <hip/hip_runtime.h>

typedef unsigned short u16;
typedef __attribute__((ext_vector_type(8))) short bf16x8;   // 8 bf16 in 4 VGPRs (MFMA A/B frag)
typedef __attribute__((ext_vector_type(4))) float f32x4;    // MFMA C/D frag

#define SS 2048
#define EE 1024
#define HH 16
#define DD 64

__device__ __forceinline__ float b2f(u16 u) {
  union { unsigned int i; float f; } v; v.i = ((unsigned int)u) << 16; return v.f;
}
__device__ __forceinline__ u16 f2b(float f) {
  union { float f; unsigned int i; } v; v.f = f;
  unsigned int i = v.i;
  return (u16)((i + 0x7FFFu + ((i >> 16) & 1u)) >> 16);  // RNE
}
__device__ __forceinline__ unsigned int cvt_pk_bf16(float lo, float hi) {
  unsigned int r;
  asm("v_cvt_pk_bf16_f32 %0, %1, %2" : "=v"(r) : "v"(lo), "v"(hi));  // RNE pack
  return r;
}

// async global->LDS, 16B per lane (m97 pattern; LDS dest = wave-uniform base + lane*16)
#define GLD16(g, l)                                                         \
  __builtin_amdgcn_global_load_lds(                                         \
      (const __attribute__((address_space(1))) unsigned int*)(g),           \
      (__attribute__((address_space(3))) unsigned int*)(l), 16, 0, 0)

// ---------------- fused prep: qkv_w cvt | trig table | LayerNorm ----------------
// blocks [0,3072): cvt qkv_w -> bf16; [3072,3076): cos/sin table; [3076,7172): LN rows
__global__ __launch_bounds__(256) void k_prep(const float* __restrict__ qkv_w,
                                              u16* __restrict__ wq_b,
                                              const float* __restrict__ inv_freq,
                                              float2* __restrict__ cs,
                                              const float* __restrict__ x,
                                              const float* __restrict__ lw,
                                              const float* __restrict__ lb,
                                              u16* __restrict__ xn) {
  const int bx = blockIdx.x, t = threadIdx.x;
  if (bx < 3072) {
    const int i = bx * 256 + t;
    float4 v = ((const float4*)qkv_w)[i];
    ushort4 o;
    o.x = f2b(v.x); o.y = f2b(v.y); o.z = f2b(v.z); o.w = f2b(v.w);
    ((ushort4*)wq_b)[i] = o;
    return;
  }
  if (bx < 3076) {
    const int i = (bx - 3072) * 256 + t;
    float th = 2048.0f * inv_freq[i];
    cs[i] = make_float2(cosf(th), sinf(th));
    return;
  }
  const int row = bx - 3076;
  float4 v = ((const float4*)(x + (size_t)row * EE))[t];
  float f0 = v.x, f1 = v.y, f2 = v.z, f3 = v.w;
  float s = f0 + f1 + f2 + f3;
  float ss = f0 * f0 + f1 * f1 + f2 * f2 + f3 * f3;
  for (int o = 1; o < 64; o <<= 1) { s += __shfl_xor(s, o); ss += __shfl_xor(ss, o); }
  __shared__ float red[8];
  int w = t >> 6;
  if ((t & 63) == 0) { red[w] = s; red[4 + w] = ss; }
  __syncthreads();
  s = red[0] + red[1] + red[2] + red[3];
  ss = red[4] + red[5] + red[6] + red[7];
  float mu = s * (1.0f / 1024.0f);
  float var = ss * (1.0f / 1024.0f) - mu * mu;
  float rstd = rsqrtf(var + 1e-5f);
  float4 wv = ((const float4*)lw)[t];
  float4 bv = ((const float4*)lb)[t];
  ushort4 o;
  o.x = f2b((f0 - mu) * rstd * wv.x + bv.x);
  o.y = f2b((f1 - mu) * rstd * wv.y + bv.y);
  o.z = f2b((f2 - mu) * rstd * wv.z + bv.z);
  o.w = f2b((f3 - mu) * rstd * wv.w + bv.w);
  ((ushort4*)(xn + (size_t)row * EE))[t] = o;
}

// ---------------- fp32 -> bf16 convert (out_w, after attn frees qkv) ----------------
__global__ __launch_bounds__(256) void k_cvt(const float* __restrict__ src,
                                             u16* __restrict__ dst) {
  const int i = blockIdx.x * 256 + threadIdx.x;
  float4 v = ((const float4*)src)[i];
  ushort4 o;
  o.x = f2b(v.x); o.y = f2b(v.y); o.z = f2b(v.z); o.w = f2b(v.w);
  ((ushort4*)dst)[i] = o;
}

// ---- MFMA GEMM  C[M,N] = A[M,K] * W[N,K]^T + bias ----
// m97 structure: BMx128 tile (BM=64 or 128), BK=32, linear LDS, global_load_lds x16
template <typename OutT, int BM64>
__device__ __forceinline__ void gemm_body(const u16* __restrict__ A,
                                          const u16* __restrict__ W,
                                          const float* __restrict__ bias,
                                          OutT* __restrict__ C,
                                          int M, int N, int K) {
  constexpr int BM = 64 * BM64;
  constexpr int MI = 2 * BM64;
  __shared__ __align__(16) u16 As[BM * 32];
  __shared__ __align__(16) u16 Ws[128 * 32];
  const int t = threadIdx.x;
  const int m0 = blockIdx.y * BM, n0 = blockIdx.x * 128;
  const int lane = t & 63, w = t >> 6, quad = lane >> 4, l15 = lane & 15;
  const int wm = (w & 1) * (BM / 2), wn = (w >> 1) * 64;

  f32x4 zero4 = {0.f, 0.f, 0.f, 0.f};
  f32x4 acc[MI][4];
  for (int mi = 0; mi < MI; mi++)
    for (int ni = 0; ni < 4; ni++) acc[mi][ni] = zero4;

  const u16* Ag = A + (size_t)(m0 + (t >> 2)) * K + (t & 3) * 8;
  const u16* Wg = W + (size_t)(n0 + (t >> 2)) * K + (t & 3) * 8;
  const size_t rowskip = (size_t)64 * K;

  for (int k0 = 0; k0 < K; k0 += 32) {
    GLD16(Ag + k0, As + t * 8);
    if constexpr (BM64 == 2) GLD16(Ag + rowskip + k0, As + 2048 + t * 8);
    GLD16(Wg + k0, Ws + t * 8);
    GLD16(Wg + rowskip + k0, Ws + 2048 + t * 8);
    __syncthreads();
    bf16x8 af[MI], wf[4];
#pragma unroll
    for (int i = 0; i < MI; i++)
      af[i] = *(const bf16x8*)(As + (wm + i * 16 + l15) * 32 + quad * 8);
#pragma unroll
    for (int i = 0; i < 4; i++)
      wf[i] = *(const bf16x8*)(Ws + (wn + i * 16 + l15) * 32 + quad * 8);
#pragma unroll
    for (int mi = 0; mi < MI; mi++)
#pragma unroll
      for (int ni = 0; ni < 4; ni++)
        acc[mi][ni] = __builtin_amdgcn_mfma_f32_16x16x32_bf16(af[mi], wf[ni], acc[mi][ni], 0, 0, 0);
    __syncthreads();
  }
  // epilogue: D row = quad*4+reg, col = l15 (verified m89 layout)
  for (int mi = 0; mi < MI; mi++)
    for (int ni = 0; ni < 4; ni++) {
      int col = n0 + wn + ni * 16 + l15;
      float bb = bias[col];
      for (int r = 0; r < 4; r++) {
        int grow = m0 + wm + mi * 16 + quad * 4 + r;
        float val = acc[mi][ni][r] + bb;
        if constexpr (sizeof(OutT) == 2) C[(size_t)grow * N + col] = f2b(val);
        else                             C[(size_t)grow * N + col] = val;
      }
    }
}

__global__ __launch_bounds__(256) void k_gemm_b(const u16* A, const u16* W,
                                                const float* bias, u16* C,
                                                int M, int N, int K) {
  gemm_body<u16, 2>(A, W, bias, C, M, N, K);
}
__global__ __launch_bounds__(256) void k_gemm_f(const u16* A, const u16* W,
                                                const float* bias, float* C,
                                                int M, int N, int K) {
  gemm_body<float, 1>(A, W, bias, C, M, N, K);
}

// ------ fused: rotate+l2norm+scale (all 4096 rows) | V transpose (blocks < 1024) ------
__global__ __launch_bounds__(256) void k_rotv(u16* __restrict__ qkv,
                                              const float2* __restrict__ cs_tab,
                                              const float* __restrict__ scale_p,
                                              u16* __restrict__ vt) {
  __shared__ float qf[1024];
  __shared__ float kf[1024];
  __shared__ __align__(16) u16 tile[64 * 72];
  const int row = blockIdx.x, t = threadIdx.x;
  {
    u16* qr = qkv + (size_t)row * 3072;
    u16* kr = qr + 1024;
    ushort4 qv = ((const ushort4*)qr)[t];
    ushort4 kv = ((const ushort4*)kr)[t];
    *(float4*)(qf + 4 * t) = make_float4(b2f(qv.x), b2f(qv.y), b2f(qv.z), b2f(qv.w));
    *(float4*)(kf + 4 * t) = make_float4(b2f(kv.x), b2f(kv.y), b2f(kv.z), b2f(kv.w));
    __syncthreads();
    const float scale = scale_p[0];
    float rq[4], rk[4];
#pragma unroll
    for (int u = 0; u < 4; u++) {
      int j = 4 * t + u;
      float2 cs = cs_tab[j];
      float qrot = (j < 512) ? -qf[2 * j + 1] : qf[2 * (j - 512)];
      float krot = (j < 512) ? -kf[2 * j + 1] : kf[2 * (j - 512)];
      rq[u] = qf[j] * cs.x + qrot * cs.y;
      rk[u] = kf[j] * cs.x + krot * cs.y;
    }
    float ssq = rq[0] * rq[0] + rq[1] * rq[1] + rq[2] * rq[2] + rq[3] * rq[3];
    float ssk = rk[0] * rk[0] + rk[1] * rk[1] + rk[2] * rk[2] + rk[3] * rk[3];
    for (int o = 1; o < 16; o <<= 1) { ssq += __shfl_xor(ssq, o); ssk += __shfl_xor(ssk, o); }
    float qs = scale / fmaxf(sqrtf(ssq), 1e-12f);
    float ks = scale / fmaxf(sqrtf(ssk), 1e-12f);
    ushort4 qo, ko;
    qo.x = f2b(rq[0] * qs); qo.y = f2b(rq[1] * qs); qo.z = f2b(rq[2] * qs); qo.w = f2b(rq[3] * qs);
    ko.x = f2b(rk[0] * ks); ko.y = f2b(rk[1] * ks); ko.z = f2b(rk[2] * ks); ko.w = f2b(rk[3] * ks);
    ((ushort4*)qr)[t] = qo;
    ((ushort4*)kr)[t] = ko;
  }
  if (row >= 1024) return;
  // ---- V transpose job (reads V section: untouched by the rotnorm phase) ----
  const int st = row & 31, bh = row >> 5;
  const int b = bh >> 4, h = bh & 15;
  const int s0 = st * 64;
  const int si = t >> 2, dc = t & 3;
  __syncthreads();  // LDS reuse safety (qf/kf reads done before tile writes)
  const u16* src = qkv + (size_t)(b * SS + s0 + si) * 3072 + 2048 + h * DD;
  bf16x8 v0 = *(const bf16x8*)(src + dc * 8);
  bf16x8 v1 = *(const bf16x8*)(src + (dc + 4) * 8);
#pragma unroll
  for (int u = 0; u < 8; u++) tile[(dc * 8 + u) * 72 + si] = (u16)v0[u];
#pragma unroll
  for (int u = 0; u < 8; u++) tile[((dc + 4) * 8 + u) * 72 + si] = (u16)v1[u];
  __syncthreads();
#pragma unroll
  for (int it = 0; it < 2; it++) {
    int idx = t + it * 256;
    int d = idx >> 3, ch = idx & 7;
    bf16x8 o = *(const bf16x8*)(tile + d * 72 + ch * 8);
    *(bf16x8*)(vt + (size_t)(bh * DD + d) * SS + s0 + ch * 8) = o;
  }
}

// ---------------- causal flash attention (MFMA) ----------------
// QBLK=64, KBLK=128 (sacc[8]): halves per-column softmax fixed cost vs KBLK=64.
// paired q-tiles (qt, 31-qt): uniform 17 iterations per block.
// sigma-permuted P/V columns (k = n*16+m  ->  m*8+n, applied to BOTH Pt cols and
// Vt k-cols; MFMA contraction is invariant to a consistent k-permutation):
// P-write = 4 cvt_pk + 1 ds_write_b128 per r (was 8 f2b + 8 ds_write_b16).
// Pt warp-private rows -> lgkmcnt-only before PV. Single-buffer LDS (53.2 KB).
__global__ __launch_bounds__(256) void k_attn(const u16* __restrict__ qkv,
                                              const u16* __restrict__ vt,
                                              u16* __restrict__ out) {
  __shared__ __align__(16) u16 Kt[128 * 72];
  __shared__ __align__(16) u16 Vt[64 * 136];
  __shared__ __align__(16) u16 Pt[64 * 136];
  const int bh = blockIdx.y;
  const int b = bh >> 4, h = bh & 15;
  const int t = threadIdx.x, w = t >> 6, lane = t & 63, quad = lane >> 4, l15 = lane & 15;
  const int kr = t >> 1, kdh = (t & 1) * 32;  // K staging: row (0..127), d-half
  const int dr = t >> 2, kc4 = t & 3;         // V staging: d-row (0..63), k-quarter
  const u16* kn = qkv + 1024;
  f32x4 zero4 = {0.f, 0.f, 0.f, 0.f};

  for (int rep = 0; rep < 2; rep++) {
    const int qt = rep ? 31 - (int)blockIdx.x : (int)blockIdx.x;
    const int q0 = qt * 64;
    const int lim = qt >> 1;  // last (diagonal) 128-wide k-tile index

    bf16x8 qf[2];
    {
      const u16* qrow = qkv + (size_t)(b * SS + q0 + 16 * w + l15) * 3072 + h * DD;
      qf[0] = *(const bf16x8*)(qrow + quad * 8);
      qf[1] = *(const bf16x8*)(qrow + 32 + quad * 8);
    }
    f32x4 oacc[4];
    for (int n = 0; n < 4; n++) oacc[n] = zero4;
    float m_i[4] = {-1e30f, -1e30f, -1e30f, -1e30f};
    float l_i[4] = {0.f, 0.f, 0.f, 0.f};

    bf16x8 kv[4], vv[4];
    // prologue: load & stage tile kt=0 (prior readers sync'd by loop-tail barriers)
    {
      const u16* krow = kn + (size_t)(b * SS + kr) * 3072 + h * DD + kdh;
      const u16* vrow = vt + (size_t)(bh * DD + dr) * SS + kc4 * 32;
#pragma unroll
      for (int j = 0; j < 4; j++) kv[j] = *(const bf16x8*)(krow + j * 8);
#pragma unroll
      for (int j = 0; j < 4; j++) vv[j] = *(const bf16x8*)(vrow + j * 8);
    }
#pragma unroll
    for (int j = 0; j < 4; j++) *(bf16x8*)(Kt + kr * 72 + kdh + j * 8) = kv[j];
#pragma unroll
    for (int j = 0; j < 4; j++) {
      const int ch = kc4 * 4 + j;
      u16* vb = Vt + dr * 136 + (ch & 1) * 64 + (ch >> 1);
#pragma unroll
      for (int e = 0; e < 8; e++) vb[e * 8] = (u16)vv[j][e];
    }
    __syncthreads();

    for (int kt = 0; kt <= lim; kt++) {
      if (kt < lim) {  // prefetch next tile into regs; consumed after barrier below
        const int k0n = (kt + 1) * 128;
        const u16* krow = kn + (size_t)(b * SS + k0n + kr) * 3072 + h * DD + kdh;
        const u16* vrow = vt + (size_t)(bh * DD + dr) * SS + k0n + kc4 * 32;
#pragma unroll
        for (int j = 0; j < 4; j++) kv[j] = *(const bf16x8*)(krow + j * 8);
#pragma unroll
        for (int j = 0; j < 4; j++) vv[j] = *(const bf16x8*)(vrow + j * 8);
      }
      f32x4 sacc[8];
#pragma unroll
      for (int n = 0; n < 8; n++) {
        sacc[n] = zero4;
#pragma unroll
        for (int c = 0; c < 2; c++) {
          bf16x8 kfrag = *(const bf16x8*)(Kt + (n * 16 + l15) * 72 + c * 32 + quad * 8);
          sacc[n] = __builtin_amdgcn_mfma_f32_16x16x32_bf16(qf[c], kfrag, sacc[n], 0, 0, 0);
        }
      }
      if (kt == lim) {  // causal mask: lcol > (qt&1)*64 + lrow
        const int rbase = (qt & 1) * 64 + 16 * w + quad * 4;
#pragma unroll
        for (int n = 0; n < 8; n++)
#pragma unroll
          for (int r = 0; r < 4; r++)
            if (n * 16 + l15 > rbase + r) sacc[n][r] = -1e30f;
      }
#pragma unroll
      for (int r = 0; r < 4; r++) {
        float mx = fmaxf(fmaxf(fmaxf(sacc[0][r], sacc[1][r]), fmaxf(sacc[2][r], sacc[3][r])),
                         fmaxf(fmaxf(sacc[4][r], sacc[5][r]), fmaxf(sacc[6][r], sacc[7][r])));
        for (int o = 1; o < 16; o <<= 1) mx = fmaxf(mx, __shfl_xor(mx, o));
        float mn = fmaxf(m_i[r], mx);
        float al = __expf(m_i[r] - mn);
        m_i[r] = mn;
        float rs = 0.f;
#pragma unroll
        for (int n = 0; n < 8; n++) {
          float p = __expf(sacc[n][r] - mn);
          sacc[n][r] = p;
          rs += p;
        }
        for (int o = 1; o < 16; o <<= 1) rs += __shfl_xor(rs, o);
        l_i[r] = al * l_i[r] + rs;
#pragma unroll
        for (int n = 0; n < 4; n++) oacc[n][r] *= al;
      }
      // P pack into sigma layout (col = l15*8 + n): 4 cvt_pk + 1 b128 store per r
#pragma unroll
      for (int r = 0; r < 4; r++) {
        union { unsigned int u[4]; bf16x8 v8; } pk;
        pk.u[0] = cvt_pk_bf16(sacc[0][r], sacc[1][r]);
        pk.u[1] = cvt_pk_bf16(sacc[2][r], sacc[3][r]);
        pk.u[2] = cvt_pk_bf16(sacc[4][r], sacc[5][r]);
        pk.u[3] = cvt_pk_bf16(sacc[6][r], sacc[7][r]);
        *(bf16x8*)(Pt + (16 * w + quad * 4 + r) * 136 + l15 * 8) = pk.v8;
      }
      // Pt rows warp-private; LDS completion only (rule 18: sched_barrier after wait)
      asm volatile("s_waitcnt lgkmcnt(0)" ::: "memory");
      __builtin_amdgcn_sched_barrier(0);
#pragma unroll
      for (int c = 0; c < 4; c++) {
        bf16x8 pf = *(const bf16x8*)(Pt + (16 * w + l15) * 136 + c * 32 + quad * 8);
#pragma unroll
        for (int n = 0; n < 4; n++) {
          bf16x8 vf = *(const bf16x8*)(Vt + (n * 16 + l15) * 136 + c * 32 + quad * 8);
          oacc[n] = __builtin_amdgcn_mfma_f32_16x16x32_bf16(pf, vf, oacc[n], 0, 0, 0);
        }
      }
      __syncthreads();  // all warps done reading Kt/Vt of tile kt
      if (kt < lim) {   // stage prefetched tile kt+1
#pragma unroll
        for (int j = 0; j < 4; j++) *(bf16x8*)(Kt + kr * 72 + kdh + j * 8) = kv[j];
#pragma unroll
        for (int j = 0; j < 4; j++) {
          const int ch = kc4 * 4 + j;
          u16* vb = Vt + dr * 136 + (ch & 1) * 64 + (ch >> 1);
#pragma unroll
          for (int e = 0; e < 8; e++) vb[e * 8] = (u16)vv[j][e];
        }
      }
      __syncthreads();  // staged tile visible
    }
    for (int n = 0; n < 4; n++)
      for (int r = 0; r < 4; r++) {
        int row = q0 + 16 * w + quad * 4 + r;
        out[(size_t)(b * SS + row) * EE + h * DD + n * 16 + l15] = f2b(oacc[n][r] / l_i[r]);
      }
  }
}

extern "C" void kernel_launch(void* const* d_in, const int* in_sizes, int n_in,
                              void* d_out, int out_size, void* d_ws, size_t ws_size,
                              hipStream_t stream) {
  const float* x       = (const float*)d_in[0];
  const float* ln_w    = (const float*)d_in[1];
  const float* ln_b    = (const float*)d_in[2];
  const float* qkv_w   = (const float*)d_in[3];
  const float* qkv_b   = (const float*)d_in[4];
  const float* qk_s    = (const float*)d_in[5];
  const float* out_w   = (const float*)d_in[6];
  const float* out_b   = (const float*)d_in[7];
  const float* inv_frq = (const float*)d_in[8];

  // ws (33.55 MB): xn bf16 [8.39 MB] | qkv bf16 [25.17 MB]
  u16* ws   = (u16*)d_ws;
  u16* xn   = ws;                               // 4096*1024 (LN out, later attn out)
  u16* qkv  = ws + (size_t)4096 * 1024;         // 4096*3072 (q,k normalized in place)
  // d_out is fp32 [16.78 MB]; stage bf16 scratch inside it while it's dead:
  u16* wq_b = (u16*)d_out;                      // [0, 6.29 MB): bf16 qkv_w
  float2* cs_tab = (float2*)((char*)d_out + 6291456);  // [6.29, 6.30 MB): cos/sin table
  u16* vt   = (u16*)d_out + (size_t)4194304;    // [8.39, 16.78 MB): bf16 V^T
  u16* wo_b = qkv;                              // bf16 out_w (qkv dead after attention)

  k_prep<<<7172, 256, 0, stream>>>(qkv_w, wq_b, inv_frq, cs_tab, x, ln_w, ln_b, xn);
  k_gemm_b<<<dim3(24, 32), 256, 0, stream>>>(xn, wq_b, qkv_b, qkv, 4096, 3072, 1024);
  k_rotv<<<4096, 256, 0, stream>>>(qkv, cs_tab, qk_s, vt);
  k_attn<<<dim3(16, 32), 256, 0, stream>>>(qkv, vt, xn);
  k_cvt<<<1024, 256, 0, stream>>>(out_w, wo_b);
  k_gemm_f<<<dim3(8, 64), 256, 0, stream>>>(xn, wo_b, out_b, (float*)d_out, 4096, 1024, 1024);
}